// Round 14
// baseline (165.185 us; speedup 1.0000x reference)
//
#include <hip/hip_runtime.h>
#include <hip/hip_bf16.h>

typedef unsigned short u16;
typedef __attribute__((ext_vector_type(8))) __bf16 bf16x8;
typedef __attribute__((ext_vector_type(4))) float f32x4;
typedef __attribute__((ext_vector_type(16))) float f32x16;
typedef __attribute__((ext_vector_type(8))) u16 u16x8;

#define BATCH 2
#define SEQ   2048
#define DIM   1024
#define HEADS 16
#define HDIM  64

#define QSCALE 0.18033688011112042f

__device__ __forceinline__ u16 f2bf(float f) {
  union { float f; unsigned int u; } v; v.f = f;
  unsigned int r = v.u + 0x7fffu + ((v.u >> 16) & 1u);
  return (u16)(r >> 16);
}
__device__ __forceinline__ unsigned int pk2(float a, float b) {
  union { __hip_bfloat162 h2; unsigned int u; } v;
  v.h2 = __float22bfloat162_rn(float2{a, b});
  return v.u;
}
__device__ __forceinline__ void pl32(unsigned &a, unsigned &b) {
  asm volatile("v_permlane32_swap_b32 %0, %1" : "+v"(a), "+v"(b));
}
__device__ __forceinline__ void async16(u16* lds, const u16* g) {
  __builtin_amdgcn_global_load_lds(
      (__attribute__((address_space(1))) void*)(void*)(g),
      (__attribute__((address_space(3))) void*)(lds), 16, 0, 0);
}

// ---------------------------------------------------------------------------
// Kernel 0: one-shot fp32 -> bf16 (RNE) conversion of x, Wq, Wk, Wv.
// ---------------------------------------------------------------------------
#define XG  524288
#define WG  131072
extern "C" __global__ __launch_bounds__(256)
void convert_all(const float* __restrict__ x,  const float* __restrict__ wq,
                 const float* __restrict__ wk, const float* __restrict__ wv,
                 u16* __restrict__ xbf, u16* __restrict__ wbf)
{
  const int g = blockIdx.x * 256 + threadIdx.x;
  const float* src; u16* dst; size_t off;
  if (g < XG)               { src = x;  dst = xbf;                 off = (size_t)g; }
  else if (g < XG + WG)     { src = wq; dst = wbf;                 off = (size_t)(g - XG); }
  else if (g < XG + 2 * WG) { src = wk; dst = wbf + DIM * DIM;     off = (size_t)(g - XG - WG); }
  else                      { src = wv; dst = wbf + 2 * DIM * DIM; off = (size_t)(g - XG - 2 * WG); }
  f32x4 a = *(const f32x4*)(src + off * 8);
  f32x4 b = *(const f32x4*)(src + off * 8 + 4);
  u16x8 o;
#pragma unroll
  for (int i = 0; i < 4; ++i) { o[i] = f2bf(a[i]); o[4 + i] = f2bf(b[i]); }
  *(u16x8*)(dst + off * 8) = o;
}

// ---------------------------------------------------------------------------
// Kernel 1: QKV projection — round-20: R11 structure + K-loop UNROLLED x3 so
// the rotating buffer indices (i0,i1,i2) are compile-time constants: LDS
// bases fold into ds_read/DMA offsets, deleting per-iter address VALU
// (theory: measured VALU load is dominated by regenerated addressing from
// the loop-carried bidx variables). Schedule identical to R11: 128x128 tile,
// triple buffer, prefetch distance 2, bottom vmcnt(4), setprio, chunk
// swizzle, XCD-clustered flat grid, packed V^T store.
// grid: flat 768  block: 256
// ---------------------------------------------------------------------------
extern "C" __global__ __launch_bounds__(256)
void qkv_gemm(const u16* __restrict__ xbf, const u16* __restrict__ wbf,
              const float* __restrict__ bq, const float* __restrict__ bk,
              const float* __restrict__ bv,
              u16* __restrict__ qo, u16* __restrict__ ko, u16* __restrict__ vto)
{
  __shared__ alignas(16) u16 Albs[3][128 * 32];
  __shared__ alignas(16) u16 Blbs[3][128 * 32];

  const int wg = blockIdx.x;
  const int p  = wg & 7;
  const int q  = wg >> 3;
  const int which = q >> 5;
  const int r  = q & 31;
  const int mBase = ((p >> 1) * 8 + (r >> 2)) * 128;
  const int nBase = ((p & 1) * 4 + (r & 3)) * 128;

  const u16* Wb = wbf + (size_t)which * DIM * DIM;
  const float* bias = (which == 0) ? bq : (which == 1) ? bk : bv;

  const int lane = threadIdx.x & 63;
  const int wave = threadIdx.x >> 6;
  const int l16  = lane & 15;
  const int quad = lane >> 4;
  const int lrow = lane >> 2;
  const int lcol = ((lane & 3) ^ ((lane >> 3) & 3)) * 8;
  const int rkey = (l16 >> 1) & 3;

  const int mw = (wave >> 1) * 64;
  const int nw = (wave & 1) * 64;

  f32x4 acc[4][4] = {};

  auto stage = [&](int bidx, int kt) {
    const int k0 = kt * 32;
#pragma unroll
    for (int pp = 0; pp < 2; ++pp) {
      const int r16 = wave * 2 + pp;
      const int row = r16 * 16 + lrow;
      async16(&Albs[bidx][r16 * 512], xbf + (size_t)(mBase + row) * DIM + k0 + lcol);
      async16(&Blbs[bidx][r16 * 512], Wb  + (size_t)(nBase + row) * DIM + k0 + lcol);
    }
  };
  auto comp = [&](int bidx) {
    bf16x8 af[4], bfr[4];
#pragma unroll
    for (int i = 0; i < 4; ++i) {
      af[i]  = *(const bf16x8*)&Albs[bidx][(mw + i * 16 + l16) * 32 + ((quad ^ rkey) * 8)];
      bfr[i] = *(const bf16x8*)&Blbs[bidx][(nw + i * 16 + l16) * 32 + ((quad ^ rkey) * 8)];
    }
    __builtin_amdgcn_s_setprio(1);
#pragma unroll
    for (int mi = 0; mi < 4; ++mi)
#pragma unroll
      for (int ni = 0; ni < 4; ++ni)
        acc[mi][ni] = __builtin_amdgcn_mfma_f32_16x16x32_bf16(af[mi], bfr[ni], acc[mi][ni], 0, 0, 0);
    __builtin_amdgcn_s_setprio(0);
  };

#define QSTEP(I0, I2, T, DO_STAGE, W4, W0, BAR) {                        \
    if (DO_STAGE) stage((I2), (T) + 2);                                  \
    comp((I0));                                                          \
    if (W4) { asm volatile("s_waitcnt vmcnt(4)" ::: "memory"); }         \
    if (W0) { asm volatile("s_waitcnt vmcnt(0)" ::: "memory"); }         \
    if (BAR) __syncthreads();                                            \
  }

  stage(0, 0);
  stage(1, 1);
  asm volatile("s_waitcnt vmcnt(4)" ::: "memory");
  __syncthreads();

  for (int t = 0; t < 30; t += 3) {
    QSTEP(0, 2, t,     1, 1, 0, 1);
    QSTEP(1, 0, t + 1, 1, 1, 0, 1);
    QSTEP(2, 1, t + 2, 1, 1, 0, 1);
  }
  QSTEP(0, 2, 30, 0, 0, 1, 1);
  QSTEP(1, 0, 31, 0, 0, 0, 0);
#undef QSTEP

  const float oscale = (which == 0) ? QSCALE : 1.0f;
#pragma unroll
  for (int ni = 0; ni < 4; ++ni) {
    const int n = nBase + nw + ni * 16 + l16;
    const float bval = bias[n];
    const int h = n >> 6, d = n & 63;
#pragma unroll
    for (int mi = 0; mi < 4; ++mi) {
      const int m0 = mBase + mw + mi * 16 + quad * 4;
      if (which == 2) {
        const int bi = m0 >> 11, s = m0 & 2047;
        uint2 pkv;
        pkv.x = pk2(acc[mi][ni][0] + bval, acc[mi][ni][1] + bval);
        pkv.y = pk2(acc[mi][ni][2] + bval, acc[mi][ni][3] + bval);
        *(uint2*)&vto[((size_t)(bi * HEADS + h) * HDIM + d) * SEQ + s] = pkv;
      } else {
        u16* dst = (which == 0) ? qo : ko;
#pragma unroll
        for (int rr = 0; rr < 4; ++rr) {
          const int m = m0 + rr;
          const int bi = m >> 11, s = m & 2047;
          dst[((size_t)(bi * HEADS + h) * SEQ + s) * HDIM + d] =
              f2bf((acc[mi][ni][rr] + bval) * oscale);
        }
      }
    }
  }
}

// ---------------------------------------------------------------------------
// Kernel 2: flash attention — round-20: R13 structure (32x32x16, key-half
// wave split, triple-buffered K/V, permlane transpose, MFMA-ones lsum,
// XCD cluster, setprio) + K-loop UNROLLED x3 (static buffer indices: LDS
// bases become immediates, deleting regenerated per-iter addressing VALU)
// + sc zero-init replaced by MFMA-into-persistent-zero (kills 16 movs/iter).
// Diagnosis: VALUBusy 46.6% = ~230 VALU instr/wave-iter vs ~35 algorithmic;
// the excess is rotation-variable addressing + init overhead.
// grid: flat 512  block: 512
// ---------------------------------------------------------------------------
extern "C" __global__ __launch_bounds__(512)
void attn(const u16* __restrict__ q, const u16* __restrict__ k,
          const u16* __restrict__ vt, float* __restrict__ out)
{
  __shared__ alignas(16) u16 KV[3][8192];
  __shared__ float Lred[8][32];

  const int lane = threadIdx.x & 63;
  const int wave = threadIdx.x >> 6;
  const int qg   = wave >> 1;
  const int wh   = wave & 1;
  const int l32  = lane & 31;
  const int khi  = lane >> 5;
  const int e7   = lane & 7;
  const int r8   = lane >> 3;
  const int sl   = lane & 7;
  const int jsw  = sl ^ (r8 & 7);

  const int wg = blockIdx.x;
  const int hb = (wg & 7) | ((wg >> 7) << 3);
  const int qb = (wg >> 3) & 15;
  const int h  = hb & 15;
  const int b  = hb >> 4;
  const int qbase = qb * 128 + qg * 32;

  const u16* qh  = q  + (size_t)(b * HEADS + h) * SEQ * HDIM;
  const u16* kh  = k  + (size_t)(b * HEADS + h) * SEQ * HDIM;
  const u16* vth = vt + (size_t)(b * HEADS + h) * HDIM * SEQ;

  union { u16x8 u; bf16x8 v; } onesu;
#pragma unroll
  for (int i = 0; i < 8; ++i) onesu.u[i] = 0x3F80;
  const bf16x8 ones = onesu.v;

  bf16x8 qf[4];
#pragma unroll
  for (int ks = 0; ks < 4; ++ks)
    qf[ks] = *(const bf16x8*)(qh + (size_t)(qbase + l32) * HDIM + ks * 16 + khi * 8);

  f32x16 o0, o1, sc, lacc, zro;
#pragma unroll
  for (int i = 0; i < 16; ++i) { o0[i] = 0.f; o1[i] = 0.f; lacc[i] = 0.f; zro[i] = 0.f; }

  auto stage = [&](int bidx, int kb) {
    async16(&KV[bidx][wave * 512],        kh  + (size_t)(kb + wave * 8 + r8) * HDIM + jsw * 8);
    async16(&KV[bidx][4096 + wave * 512], vth + (size_t)(wave * 8 + r8) * SEQ + kb + jsw * 8);
  };

  const int krow64 = (wh * 32 + l32) * 64;
  auto qkt = [&](const u16* Kb) {
    bf16x8 kf0 = *(const bf16x8*)&Kb[krow64 + (((0 + khi) ^ e7) * 8)];
    sc = __builtin_amdgcn_mfma_f32_32x32x16_bf16(kf0, qf[0], zro, 0, 0, 0);
#pragma unroll
    for (int ks = 1; ks < 4; ++ks) {
      bf16x8 kf = *(const bf16x8*)&Kb[krow64 + (((ks * 2 + khi) ^ e7) * 8)];
      sc = __builtin_amdgcn_mfma_f32_32x32x16_bf16(kf, qf[ks], sc, 0, 0, 0);
    }
  };

  const int rowV0 = l32 * 64;
  const int rowV1 = (32 + l32) * 64;

#define ASTEP(I0, I1, I2, T, DO_STAGE, DO_QKT, W2, W0, BAR) {            \
    if (DO_STAGE) stage((I2), ((T) + 2) * 64);                           \
    bf16x8 pa[2];                                                        \
    _Pragma("unroll")                                                    \
    for (int s = 0; s < 2; ++s) {                                        \
      const float p0 = __builtin_amdgcn_exp2f(sc[8 * s + 0]);            \
      const float p1 = __builtin_amdgcn_exp2f(sc[8 * s + 1]);            \
      const float p2 = __builtin_amdgcn_exp2f(sc[8 * s + 2]);            \
      const float p3 = __builtin_amdgcn_exp2f(sc[8 * s + 3]);            \
      const float p4 = __builtin_amdgcn_exp2f(sc[8 * s + 4]);            \
      const float p5 = __builtin_amdgcn_exp2f(sc[8 * s + 5]);            \
      const float p6 = __builtin_amdgcn_exp2f(sc[8 * s + 6]);            \
      const float p7 = __builtin_amdgcn_exp2f(sc[8 * s + 7]);            \
      unsigned u0 = pk2(p0, p1), u1 = pk2(p2, p3);                       \
      unsigned v0 = pk2(p4, p5), v1 = pk2(p6, p7);                       \
      pl32(u0, v0); pl32(u1, v1);                                        \
      union { uint4 uu; bf16x8 vv; } cvt;                                \
      cvt.uu = uint4{u0, u1, v0, v1};                                    \
      pa[s] = cvt.vv;                                                    \
    }                                                                    \
    __builtin_amdgcn_s_setprio(1);                                       \
    if (DO_QKT) qkt(&KV[I1][0]);                                         \
    {                                                                    \
      const u16* Vb = &KV[I0][4096];                                     \
      _Pragma("unroll")                                                  \
      for (int s = 0; s < 2; ++s) {                                      \
        const int c = wh * 4 + s * 2 + khi;                              \
        bf16x8 vf0 = *(const bf16x8*)&Vb[rowV0 + ((c ^ e7) * 8)];        \
        bf16x8 vf1 = *(const bf16x8*)&Vb[rowV1 + ((c ^ e7) * 8)];        \
        o0 = __builtin_amdgcn_mfma_f32_32x32x16_bf16(pa[s], vf0, o0, 0, 0, 0); \
        o1 = __builtin_amdgcn_mfma_f32_32x32x16_bf16(pa[s], vf1, o1, 0, 0, 0); \
        lacc = __builtin_amdgcn_mfma_f32_32x32x16_bf16(pa[s], ones, lacc, 0, 0, 0); \
      }                                                                  \
    }                                                                    \
    __builtin_amdgcn_s_setprio(0);                                       \
    if (W2) { asm volatile("s_waitcnt vmcnt(2)" ::: "memory"); }         \
    if (W0) { asm volatile("s_waitcnt vmcnt(0)" ::: "memory"); }         \
    if (BAR) __syncthreads();                                            \
  }

  stage(0, 0);
  stage(1, 64);
  asm volatile("s_waitcnt vmcnt(2)" ::: "memory");
  __syncthreads();
  qkt(&KV[0][0]);

  for (int t = 0; t < 30; t += 3) {
    ASTEP(0, 1, 2, t,     1, 1, 1, 0, 1);
    ASTEP(1, 2, 0, t + 1, 1, 1, 1, 0, 1);
    ASTEP(2, 0, 1, t + 2, 1, 1, 1, 0, 1);
  }
  ASTEP(0, 1, 2, 30, 0, 1, 0, 1, 1);
  ASTEP(1, 2, 0, 31, 0, 0, 0, 0, 0);
#undef ASTEP

  // ---- epilogue: publish lsum (col-invariant rowsums), merge halves ----
  if (l32 == 0) {
#pragma unroll
    for (int r = 0; r < 16; ++r)
      Lred[wave][(r & 3) + 8 * (r >> 2) + 4 * khi] = lacc[r];
  }

  __syncthreads();
  {
    float* myslot = (float*)&KV[0][0] + wave * 1024;
    const f32x16 ship = wh ? o0 : o1;
#pragma unroll
    for (int c = 0; c < 4; ++c) {
      f32x4 t;
      t[0] = ship[4 * c]; t[1] = ship[4 * c + 1];
      t[2] = ship[4 * c + 2]; t[3] = ship[4 * c + 3];
      *(f32x4*)&myslot[c * 256 + lane * 4] = t;
    }
  }
  __syncthreads();
  f32x16 own = wh ? o1 : o0;
  {
    const float* ps = (float*)&KV[0][0] + (wave ^ 1) * 1024;
#pragma unroll
    for (int c = 0; c < 4; ++c) {
      f32x4 t = *(const f32x4*)&ps[c * 256 + lane * 4];
      own[4 * c] += t[0]; own[4 * c + 1] += t[1];
      own[4 * c + 2] += t[2]; own[4 * c + 3] += t[3];
    }
  }

  {
    const int d = wh * 32 + l32;
    const float* lr0 = &Lred[qg * 2][0];
    const float* lr1 = &Lred[qg * 2 + 1][0];
#pragma unroll
    for (int r = 0; r < 16; ++r) {
      const int qv = (r & 3) + 8 * (r >> 2) + 4 * khi;
      const float inv = 1.f / fmaxf(lr0[qv] + lr1[qv], 1e-20f);
      out[((size_t)(b * SEQ + qbase + qv) * HEADS + h) * HDIM + d] = own[r] * inv;
    }
  }
}

extern "C" void kernel_launch(void* const* d_in, const int* in_sizes, int n_in,
                              void* d_out, int out_size, void* d_ws, size_t ws_size,
                              hipStream_t stream) {
  (void)in_sizes; (void)n_in; (void)out_size; (void)ws_size;
  const float* x  = (const float*)d_in[0];
  const float* Wq = (const float*)d_in[1];
  const float* bq = (const float*)d_in[2];
  const float* Wk = (const float*)d_in[3];
  const float* bk = (const float*)d_in[4];
  const float* Wv = (const float*)d_in[5];
  const float* bv = (const float*)d_in[6];
  float* out = (float*)d_out;

  u16* ws = (u16*)d_ws;
  const size_t XSZ = (size_t)BATCH * SEQ * DIM;
  const size_t WSZ = (size_t)DIM * DIM;
  const size_t QSZ = (size_t)BATCH * HEADS * SEQ * HDIM;
  u16* xbf   = ws;
  u16* wbf   = ws + XSZ;
  u16* qbuf  = ws + XSZ + 3 * WSZ;
  u16* kbuf  = qbuf + QSZ;
  u16* vtbuf = kbuf + QSZ;

  convert_all<<<3584, 256, 0, stream>>>(x, Wq, Wk, Wv, xbf, wbf);

  qkv_gemm<<<768, 256, 0, stream>>>(xbf, wbf, bq, bk, bv, qbuf, kbuf, vtbuf);

  attn<<<512, 512, 0, stream>>>(qbuf, kbuf, vtbuf, out);
}